// Round 11
// baseline (340.813 us; speedup 1.0000x reference)
//
#include <hip/hip_runtime.h>

// Transformer decoder block, MI355X gfx950. Round 11: all weight casts and the
// X transpose folded INTO consumer GEMMs (f32 reg-staging / scr-transpose
// staging, sim-style race-free 2-barrier schedule). prep = Wq/Wk transposes only.
//
// Dataflow:
//   WqT,WkT = transpose(Wq,Wk) bf16 [tiled]; G2 = WkT·WqT^T (split-K)
//   e   = Xt-staged(X f32) · G2^T     (B,N,C)  bf16
//   E   = exp((e·T^T-staged)/32)      (B,N,L)  bf16 + row-sum partials
//   u   = (E · T-staged) / rowsum     (B,N,C)  bf16
//   Z1  = Wv(f32-staged) · u^T + X    (B,C,N)  bf16 + stats pp1
//   XoutT = LN(Z1) bf16 (N,C) [tiled]
//   hT  = relu(XoutT · Wf1(f32-staged)^T)  (B,N,C) bf16
//   Z2  = transpose(hT · Wf2(f32-staged)^T) + LN(Z1)  bf16 + pp2
//   out = LN(Z2) f32

using bf16   = __bf16;
using bf16x4 = __attribute__((ext_vector_type(4))) __bf16;
using bf16x8 = __attribute__((ext_vector_type(8))) __bf16;
using f32x4  = __attribute__((ext_vector_type(4))) float;

static constexpr int  Bb = 64;
static constexpr int  Cc = 1024;
static constexpr int  Nn = 128;
static constexpr int  Ll = 512;
static constexpr long long PLANE = (long long)Cc * Nn;
static constexpr float INV_PLANE = 1.0f / 131072.0f;

__device__ __forceinline__ void gload_lds16(const void* g, void* l) {
    __builtin_amdgcn_global_load_lds(
        (__attribute__((address_space(1))) void*)g,
        (__attribute__((address_space(3))) void*)l,
        16, 0, 0);
}

// ---------------- prep: Wq/Wk transposes only (tiled bf16) ----------------
__global__ void __launch_bounds__(256)
prep_w(const float* __restrict__ Wq, const float* __restrict__ Wk,
       bf16* __restrict__ WqT, bf16* __restrict__ WkT) {
    __shared__ float tile[64][65];
    int j = blockIdx.x;
    const float* in = (j >= 256) ? Wk : Wq;
    bf16* outT      = (j >= 256) ? WkT : WqT;
    j &= 255;
    int bxx = j & 15, byy = j >> 4;
    int s0 = bxx * 64, r0 = byy * 64;
    int t = threadIdx.x;
    int rl = t >> 4, sc = (t & 15) * 4;
    #pragma unroll
    for (int p = 0; p < 4; ++p) {
        int r = p * 16 + rl;
        float4 v = *(const float4*)(in + (long long)(r0 + r) * Cc + s0 + sc);
        *(float4*)&tile[r][sc] = v;
    }
    __syncthreads();
    long long tb = ((long long)(s0 >> 6) * (Cc >> 6) + (r0 >> 6)) * 4096;
    int sb = t >> 3, rg = (t & 7) * 8;
    #pragma unroll
    for (int p = 0; p < 2; ++p) {
        int s = sb + p * 32;
        bf16x8 o;
        #pragma unroll
        for (int jj = 0; jj < 8; ++jj) o[jj] = (bf16)tile[rg + jj][s];
        *(bf16x8*)(outT + tb + s * 64 + rg) = o;
    }
}

// ---------------- generic TN GEMM core (used for G2 split-K only) ----------------
#define GEMM_PROLOGUE_AND_LOOP(A_, Bt_, KLOOP_, LD_, TA_, TB_)                     \
    __shared__ bf16 As[2][128 * 64];                                               \
    __shared__ bf16 Bs[2][128 * 64];                                               \
    const int n0   = blockIdx.x * 128;                                             \
    const int m0   = blockIdx.y * 128;                                             \
    const int t    = threadIdx.x;                                                  \
    const int lane = t & 63;                                                       \
    const int w    = t >> 6;                                                       \
    const int wr   = (w >> 1) * 64;                                                \
    const int wc   = (w & 1) * 64;                                                 \
    const int lr   = lane & 15;                                                    \
    const int hi4  = (lane >> 4) * 16;                                             \
    const int sw   = (lr & 7) << 4;                                                \
    const int stepA_ = (TA_) ? 4096 : 64;                                          \
    const int stepB_ = (TB_) ? 4096 : 64;                                          \
    const bf16* gA[4]; const bf16* gB[4]; int lo[4];                               \
    _Pragma("unroll")                                                              \
    for (int p = 0; p < 4; ++p) {                                                  \
        int o = w * 1024 + lane * 16 + p * 4096;                                   \
        int row = o >> 7;                                                          \
        int scol = ((o & 127) ^ ((row & 7) << 4)) >> 1;                            \
        lo[p] = o;                                                                 \
        int ra = m0 + row, rb = n0 + row;                                          \
        gA[p] = (TA_) ? A_ + ((long long)(ra >> 6) * (LD_ >> 6)) * 4096            \
                           + (ra & 63) * 64 + scol                                 \
                      : A_ + (long long)ra * LD_ + scol;                           \
        gB[p] = (TB_) ? Bt_ + ((long long)(rb >> 6) * (LD_ >> 6)) * 4096           \
                            + (rb & 63) * 64 + scol                                \
                      : Bt_ + (long long)rb * LD_ + scol;                          \
    }                                                                              \
    f32x4 acc[4][4] = {};                                                          \
    const int NT_ = KLOOP_ / 64;                                                   \
    _Pragma("unroll")                                                              \
    for (int p = 0; p < 4; ++p) gload_lds16(gA[p], (char*)As[0] + lo[p]);          \
    _Pragma("unroll")                                                              \
    for (int p = 0; p < 4; ++p) gload_lds16(gB[p], (char*)Bs[0] + lo[p]);          \
    __syncthreads();                                                               \
    int cur_ = 0;                                                                  \
    for (int kt = 0; kt < NT_; ++kt) {                                             \
        if (kt + 1 < NT_) {                                                        \
            _Pragma("unroll")                                                      \
            for (int p = 0; p < 4; ++p)                                            \
                gload_lds16(gA[p] + (long long)(kt + 1) * stepA_,                  \
                            (char*)As[cur_ ^ 1] + lo[p]);                          \
            _Pragma("unroll")                                                      \
            for (int p = 0; p < 4; ++p)                                            \
                gload_lds16(gB[p] + (long long)(kt + 1) * stepB_,                  \
                            (char*)Bs[cur_ ^ 1] + lo[p]);                          \
        }                                                                          \
        const bf16* As_ = As[cur_]; const bf16* Bs_ = Bs[cur_];                    \
        _Pragma("unroll")                                                          \
        for (int kk = 0; kk < 2; ++kk) {                                           \
            bf16x8 af[4], bfr[4];                                                  \
            _Pragma("unroll")                                                      \
            for (int i = 0; i < 4; ++i) {                                          \
                int ra = wr + i * 16 + lr;                                         \
                int rb = wc + i * 16 + lr;                                         \
                af[i]  = *(const bf16x8*)((const char*)As_ +                       \
                          ((((ra << 7) + (kk << 6) + hi4)) ^ sw));                 \
                bfr[i] = *(const bf16x8*)((const char*)Bs_ +                       \
                          ((((rb << 7) + (kk << 6) + hi4)) ^ sw));                 \
            }                                                                      \
            _Pragma("unroll")                                                      \
            for (int mi = 0; mi < 4; ++mi)                                         \
                _Pragma("unroll")                                                  \
                for (int ni = 0; ni < 4; ++ni)                                     \
                    acc[mi][ni] = __builtin_amdgcn_mfma_f32_16x16x32_bf16(         \
                        af[mi], bfr[ni], acc[mi][ni], 0, 0, 0);                    \
        }                                                                          \
        __syncthreads();                                                           \
        cur_ ^= 1;                                                                 \
    }

template <typename OutT, bool RELU, int TA, int TB>
__global__ void __launch_bounds__(256, 2)
gemm_tn(const bf16* __restrict__ A, const bf16* __restrict__ Bt, OutT* __restrict__ C,
        int M, int N, int KLOOP, int ld, long long sA, long long sBt, long long sC,
        float scale) {
    A  += (long long)blockIdx.z * sA;
    Bt += (long long)blockIdx.z * sBt;
    C  += (long long)blockIdx.z * sC;
    GEMM_PROLOGUE_AND_LOOP(A, Bt, KLOOP, ld, TA, TB)
    const int rbase = m0 + wr + (lane >> 4) * 4;
    const int cbase = n0 + wc + lr;
    #pragma unroll
    for (int mi = 0; mi < 4; ++mi)
        #pragma unroll
        for (int ni = 0; ni < 4; ++ni)
            #pragma unroll
            for (int r = 0; r < 4; ++r) {
                float v = acc[mi][ni][r] * scale;
                if (RELU) v = fmaxf(v, 0.0f);
                C[(long long)(rbase + mi * 16 + r) * N + (cbase + ni * 16)] = (OutT)v;
            }
}

__global__ void g2_reduce(const float* __restrict__ p, bf16* __restrict__ g2) {
    int i = (blockIdx.x * 256 + threadIdx.x) * 4;
    float4 a = *(const float4*)(p + i);
    float4 b = *(const float4*)(p + 1048576 + i);
    float4 c = *(const float4*)(p + 2097152 + i);
    float4 d = *(const float4*)(p + 3145728 + i);
    bf16x4 o = { (bf16)(a.x + b.x + c.x + d.x), (bf16)(a.y + b.y + c.y + d.y),
                 (bf16)(a.z + b.z + c.z + d.z), (bf16)(a.w + b.w + c.w + d.w) };
    *(bf16x4*)(g2 + i) = o;
}

// ---------------- e GEMM: A = X f32 transpose-staged (scr); B = G2 bf16 gload ----------------
// e[n,c'] (128 x 1024), grid (8,1,64). 2-barrier sim-style schedule.
__global__ void __launch_bounds__(256, 2)
gemm_e(const float* __restrict__ Xg, const bf16* __restrict__ G2, bf16* __restrict__ e) {
    __shared__ char smem[49664];              // As 16384 + Bs 16384 + scr 16640
    bf16* Asl = (bf16*)smem;
    bf16* Bs  = (bf16*)(smem + 16384);
    bf16* scr = (bf16*)(smem + 32768);        // [64][130] bf16
    Xg += (long long)blockIdx.z * PLANE;
    e  += (long long)blockIdx.z * ((long long)Nn * Cc);
    const int n0 = blockIdx.x * 128;          // c' offset
    const int t = threadIdx.x, lane = t & 63, w = t >> 6;
    const int wr = (w >> 1) * 64, wc = (w & 1) * 64;
    const int lr = lane & 15, hi4 = (lane >> 4) * 16, sw = (lr & 7) << 4;
    const bf16* gB[4]; int lo[4];
    #pragma unroll
    for (int p = 0; p < 4; ++p) {
        int o = w * 1024 + lane * 16 + p * 4096;
        int row = o >> 7;
        int scol = ((o & 127) ^ ((row & 7) << 4)) >> 1;
        lo[p] = o;
        gB[p] = G2 + (long long)(n0 + row) * Cc + scol;
    }
    const int s_c = t >> 2, s_n = (t & 3) * 32;    // X stage: c-row (64), n-base
    float4 xreg[8];
    #pragma unroll
    for (int i = 0; i < 8; ++i)
        xreg[i] = *(const float4*)(Xg + (long long)s_c * Nn + s_n + i * 4);
    f32x4 acc[4][4] = {};
    const int NT = Cc / 64;
    for (int kt = 0; kt < NT; ++kt) {
        #pragma unroll
        for (int i = 0; i < 8; ++i) {
            float4 v = xreg[i];
            bf16x4 o = { (bf16)v.x, (bf16)v.y, (bf16)v.z, (bf16)v.w };
            *(bf16x4*)(scr + s_c * 130 + s_n + i * 4) = o;
        }
        __syncthreads();   // B1
        #pragma unroll
        for (int p = 0; p < 4; ++p) gload_lds16(gB[p] + kt * 64, (char*)Bs + lo[p]);
        {   // As build: transpose scr -> As[n][c], swizzled
            int nrow = t & 127;
            #pragma unroll
            for (int g = 0; g < 4; ++g) {
                int c0 = (t >> 7) * 32 + g * 8;
                bf16x8 bv;
                #pragma unroll
                for (int j = 0; j < 8; ++j) bv[j] = scr[(c0 + j) * 130 + nrow];
                *(bf16x8*)((char*)Asl + (((nrow << 7) + c0 * 2) ^ ((nrow & 7) << 4))) = bv;
            }
        }
        if (kt + 1 < NT) {
            #pragma unroll
            for (int i = 0; i < 8; ++i)
                xreg[i] = *(const float4*)(Xg + (long long)((kt + 1) * 64 + s_c) * Nn
                                           + s_n + i * 4);
        }
        __syncthreads();   // B2
        #pragma unroll
        for (int kk = 0; kk < 2; ++kk) {
            bf16x8 af[4], bfr[4];
            #pragma unroll
            for (int i = 0; i < 4; ++i) {
                int ra = wr + i * 16 + lr;
                int rb = wc + i * 16 + lr;
                af[i]  = *(const bf16x8*)((const char*)Asl + (((ra << 7) + (kk << 6) + hi4) ^ sw));
                bfr[i] = *(const bf16x8*)((const char*)Bs  + (((rb << 7) + (kk << 6) + hi4) ^ sw));
            }
            #pragma unroll
            for (int mi = 0; mi < 4; ++mi)
                #pragma unroll
                for (int ni = 0; ni < 4; ++ni)
                    acc[mi][ni] = __builtin_amdgcn_mfma_f32_16x16x32_bf16(
                        af[mi], bfr[ni], acc[mi][ni], 0, 0, 0);
        }
    }
    const int rbase = wr + (lane >> 4) * 4;
    const int cbase = n0 + wc + lr;
    #pragma unroll
    for (int mi = 0; mi < 4; ++mi)
        #pragma unroll
        for (int ni = 0; ni < 4; ++ni)
            #pragma unroll
            for (int r = 0; r < 4; ++r)
                e[(long long)(rbase + mi * 16 + r) * Cc + (cbase + ni * 16)] =
                    (bf16)acc[mi][ni][r];
}

// ---------------- sim GEMM: 128(n) x 64(l), A = e gload; B = T f32 scr-transpose ----------------
__global__ void __launch_bounds__(256, 2)
gemm_sim_exp(const bf16* __restrict__ A /*e*/, const float* __restrict__ Tg,
             bf16* __restrict__ E, float* __restrict__ rspart) {
    __shared__ char smem[33024];
    bf16* Asb = (bf16*)smem;
    bf16* Bs  = (bf16*)(smem + 16384);
    bf16* scr = (bf16*)(smem + 24576);         // [64][66]
    A  += (long long)blockIdx.z * ((long long)Nn * Cc);
    Tg += (long long)blockIdx.z * ((long long)Cc * Ll);
    E  += (long long)blockIdx.z * ((long long)Nn * Ll);
    const int l0 = blockIdx.x * 64;
    const int t = threadIdx.x, lane = t & 63, w = t >> 6;
    const int lr = lane & 15, hi4 = (lane >> 4) * 16, sw = (lr & 7) << 4;
    const bf16* gA[4]; int lo[4];
    #pragma unroll
    for (int p = 0; p < 4; ++p) {
        int o = w * 1024 + lane * 16 + p * 4096;
        int row = o >> 7;
        int scol = ((o & 127) ^ ((row & 7) << 4)) >> 1;
        lo[p] = o;
        gA[p] = A + (long long)row * Cc + scol;
    }
    const int s_c = t >> 2, s_l = (t & 3) * 16;
    float4 treg[4];
    #pragma unroll
    for (int i = 0; i < 4; ++i)
        treg[i] = *(const float4*)(Tg + (long long)s_c * Ll + l0 + s_l + i * 4);
    f32x4 acc[2][4] = {};
    const int NT = Cc / 64;
    for (int kt = 0; kt < NT; ++kt) {
        #pragma unroll
        for (int i = 0; i < 4; ++i) {
            float4 v = treg[i];
            bf16x4 o = { (bf16)v.x, (bf16)v.y, (bf16)v.z, (bf16)v.w };
            *(bf16x4*)(scr + s_c * 66 + s_l + i * 4) = o;
        }
        __syncthreads();
        #pragma unroll
        for (int p = 0; p < 4; ++p) gload_lds16(gA[p] + kt * 64, (char*)Asb + lo[p]);
        {
            int lrow = t & 63;
            #pragma unroll
            for (int p = 0; p < 2; ++p) {
                int c8 = (t >> 6) * 16 + p * 8;
                bf16x8 bv;
                #pragma unroll
                for (int j = 0; j < 8; ++j) bv[j] = scr[(c8 + j) * 66 + lrow];
                *(bf16x8*)((char*)Bs + (((lrow << 7) + c8 * 2) ^ ((lrow & 7) << 4))) = bv;
            }
        }
        if (kt + 1 < NT) {
            #pragma unroll
            for (int i = 0; i < 4; ++i)
                treg[i] = *(const float4*)(Tg + (long long)((kt + 1) * 64 + s_c) * Ll
                                           + l0 + s_l + i * 4);
        }
        __syncthreads();
        #pragma unroll
        for (int kk = 0; kk < 2; ++kk) {
            bf16x8 af[2], bfr[4];
            #pragma unroll
            for (int mi = 0; mi < 2; ++mi) {
                int ra = w * 32 + mi * 16 + lr;
                af[mi] = *(const bf16x8*)((const char*)Asb + (((ra << 7) + (kk << 6) + hi4) ^ sw));
            }
            #pragma unroll
            for (int ni = 0; ni < 4; ++ni) {
                int rb = ni * 16 + lr;
                bfr[ni] = *(const bf16x8*)((const char*)Bs + (((rb << 7) + (kk << 6) + hi4) ^ sw));
            }
            #pragma unroll
            for (int mi = 0; mi < 2; ++mi)
                #pragma unroll
                for (int ni = 0; ni < 4; ++ni)
                    acc[mi][ni] = __builtin_amdgcn_mfma_f32_16x16x32_bf16(
                        af[mi], bfr[ni], acc[mi][ni], 0, 0, 0);
        }
    }
    float psum[2][4];
    #pragma unroll
    for (int mi = 0; mi < 2; ++mi)
        #pragma unroll
        for (int r = 0; r < 4; ++r) psum[mi][r] = 0.f;
    #pragma unroll
    for (int mi = 0; mi < 2; ++mi)
        #pragma unroll
        for (int ni = 0; ni < 4; ++ni)
            #pragma unroll
            for (int r = 0; r < 4; ++r) {
                int row = w * 32 + mi * 16 + (lane >> 4) * 4 + r;
                float ev = __expf(acc[mi][ni][r] * 0.03125f);
                E[(long long)row * Ll + l0 + ni * 16 + lr] = (bf16)ev;
                psum[mi][r] += ev;
            }
    #pragma unroll
    for (int mi = 0; mi < 2; ++mi)
        #pragma unroll
        for (int r = 0; r < 4; ++r) {
            float v = psum[mi][r];
            v += __shfl_xor(v, 1); v += __shfl_xor(v, 2);
            v += __shfl_xor(v, 4); v += __shfl_xor(v, 8);
            psum[mi][r] = v;
        }
    if (lr == 0) {
        float* rp = rspart + ((long long)blockIdx.z * 8 + blockIdx.x) * 128;
        #pragma unroll
        for (int mi = 0; mi < 2; ++mi)
            #pragma unroll
            for (int r = 0; r < 4; ++r)
                rp[w * 32 + mi * 16 + (lane >> 4) * 4 + r] = psum[mi][r];
    }
}

// ---------------- u GEMM: 128(n) x 64(c), A = E gload dbuf; B = T f32 reg-staged ----------------
__global__ void __launch_bounds__(256, 4)
gemm_u_scaled(const bf16* __restrict__ A /*E*/, const float* __restrict__ Tg,
              bf16* __restrict__ C, const float* __restrict__ rspart) {
    __shared__ char smem[40960];
    bf16* AsB = (bf16*)smem;
    bf16* Bs  = (bf16*)(smem + 32768);
    A  += (long long)blockIdx.z * ((long long)Nn * Ll);
    Tg += (long long)blockIdx.z * ((long long)Cc * Ll);
    C  += (long long)blockIdx.z * ((long long)Nn * Cc);
    const float* rp = rspart + (long long)blockIdx.z * 1024;
    const int c0 = blockIdx.x * 64;
    const int t = threadIdx.x, lane = t & 63, w = t >> 6;
    const int lr = lane & 15, hi4 = (lane >> 4) * 16, sw = (lr & 7) << 4;
    const bf16* gA[4]; int lo[4];
    #pragma unroll
    for (int p = 0; p < 4; ++p) {
        int o = w * 1024 + lane * 16 + p * 4096;
        int row = o >> 7;
        int scol = ((o & 127) ^ ((row & 7) << 4)) >> 1;
        lo[p] = o;
        gA[p] = A + (long long)row * Ll + scol;
    }
    const int s_c = t >> 2, s_l = (t & 3) * 16;
    float4 treg[4];
    #pragma unroll
    for (int p = 0; p < 4; ++p) gload_lds16(gA[p], (char*)AsB + lo[p]);
    #pragma unroll
    for (int i = 0; i < 4; ++i)
        treg[i] = *(const float4*)(Tg + (long long)(c0 + s_c) * Ll + s_l + i * 4);
    f32x4 acc[2][4] = {};
    int cur = 0;
    const int NT = Ll / 64;
    for (int kt = 0; kt < NT; ++kt) {
        if (kt + 1 < NT) {
            #pragma unroll
            for (int p = 0; p < 4; ++p)
                gload_lds16(gA[p] + (kt + 1) * 64, (char*)AsB + (cur ^ 1) * 16384 + lo[p]);
        }
        __syncthreads();
        #pragma unroll
        for (int p = 0; p < 2; ++p) {
            bf16x8 bv;
            #pragma unroll
            for (int j = 0; j < 4; ++j) {
                bv[j]     = (bf16)((const float*)&treg[p * 2])[j];
                bv[4 + j] = (bf16)((const float*)&treg[p * 2 + 1])[j];
            }
            *(bf16x8*)((char*)Bs + (((s_c << 7) + (s_l + p * 8) * 2) ^ ((s_c & 7) << 4))) = bv;
        }
        if (kt + 1 < NT) {
            #pragma unroll
            for (int i = 0; i < 4; ++i)
                treg[i] = *(const float4*)(Tg + (long long)(c0 + s_c) * Ll
                                           + (kt + 1) * 64 + s_l + i * 4);
        }
        __syncthreads();
        const bf16* As_ = AsB + cur * 8192;
        #pragma unroll
        for (int kk = 0; kk < 2; ++kk) {
            bf16x8 af[2], bfr[4];
            #pragma unroll
            for (int mi = 0; mi < 2; ++mi) {
                int ra = w * 32 + mi * 16 + lr;
                af[mi] = *(const bf16x8*)((const char*)As_ + (((ra << 7) + (kk << 6) + hi4) ^ sw));
            }
            #pragma unroll
            for (int ni = 0; ni < 4; ++ni) {
                int rb = ni * 16 + lr;
                bfr[ni] = *(const bf16x8*)((const char*)Bs + (((rb << 7) + (kk << 6) + hi4) ^ sw));
            }
            #pragma unroll
            for (int mi = 0; mi < 2; ++mi)
                #pragma unroll
                for (int ni = 0; ni < 4; ++ni)
                    acc[mi][ni] = __builtin_amdgcn_mfma_f32_16x16x32_bf16(
                        af[mi], bfr[ni], acc[mi][ni], 0, 0, 0);
        }
        cur ^= 1;
    }
    #pragma unroll
    for (int mi = 0; mi < 2; ++mi)
        #pragma unroll
        for (int r = 0; r < 4; ++r) {
            int row = w * 32 + mi * 16 + (lane >> 4) * 4 + r;
            float s = 0.f;
            #pragma unroll
            for (int j = 0; j < 8; ++j) s += rp[j * 128 + row];
            float inv = 1.f / s;
            #pragma unroll
            for (int ni = 0; ni < 4; ++ni)
                C[(long long)row * Cc + (c0 + ni * 16 + lr)] = (bf16)(acc[mi][ni][r] * inv);
        }
}

// ---------------- ctx GEMM + LN1: A = Wv f32 reg-staged; B = u bf16 gload ----------------
// Z1[c,n] = (Wv·u^T)[c,n] + X[c,n] bf16 + stats. grid (1,8,64), m0 = by*128.
__global__ void __launch_bounds__(256, 2)
gemm_ctx_ln1(const float* __restrict__ Wv, const bf16* __restrict__ U,
             const float* __restrict__ X, bf16* __restrict__ Z1, float* __restrict__ partials) {
    __shared__ char smem[32768];              // As 16384 + Bs 16384
    bf16* Asl = (bf16*)smem;
    bf16* Bs  = (bf16*)(smem + 16384);
    U  += (long long)blockIdx.z * ((long long)Nn * Cc);
    X  += (long long)blockIdx.z * PLANE;
    Z1 += (long long)blockIdx.z * PLANE;
    const int m0 = blockIdx.y * 128;          // c rows
    const int t = threadIdx.x, lane = t & 63, w = t >> 6;
    const int wr = (w >> 1) * 64, wc = (w & 1) * 64;
    const int lr = lane & 15, hi4 = (lane >> 4) * 16, sw = (lr & 7) << 4;
    const bf16* gB[4]; int lo[4];
    #pragma unroll
    for (int p = 0; p < 4; ++p) {
        int o = w * 1024 + lane * 16 + p * 4096;
        int row = o >> 7;
        int scol = ((o & 127) ^ ((row & 7) << 4)) >> 1;
        lo[p] = o;
        gB[p] = U + (long long)row * Cc + scol;   // n rows
    }
    const int s_r = t >> 1, s_k = (t & 1) * 32;   // Wv stage: row (128), k-base
    float4 wreg[8];
    #pragma unroll
    for (int i = 0; i < 8; ++i)
        wreg[i] = *(const float4*)(Wv + (long long)(m0 + s_r) * Cc + s_k + i * 4);
    f32x4 acc[4][4] = {};
    const int NT = Cc / 64;
    for (int kt = 0; kt < NT; ++kt) {
        __syncthreads();   // B1: prior MFMA reads done
        #pragma unroll
        for (int p = 0; p < 4; ++p) gload_lds16(gB[p] + kt * 64, (char*)Bs + lo[p]);
        #pragma unroll
        for (int p = 0; p < 4; ++p) {
            int kc = s_k + p * 8;
            bf16x8 bv;
            #pragma unroll
            for (int j = 0; j < 4; ++j) {
                bv[j]     = (bf16)((const float*)&wreg[p * 2])[j];
                bv[4 + j] = (bf16)((const float*)&wreg[p * 2 + 1])[j];
            }
            *(bf16x8*)((char*)Asl + (((s_r << 7) + kc * 2) ^ ((s_r & 7) << 4))) = bv;
        }
        if (kt + 1 < NT) {
            #pragma unroll
            for (int i = 0; i < 8; ++i)
                wreg[i] = *(const float4*)(Wv + (long long)(m0 + s_r) * Cc
                                           + (kt + 1) * 64 + s_k + i * 4);
        }
        __syncthreads();   // B2
        #pragma unroll
        for (int kk = 0; kk < 2; ++kk) {
            bf16x8 af[4], bfr[4];
            #pragma unroll
            for (int i = 0; i < 4; ++i) {
                int ra = wr + i * 16 + lr;
                int rb = wc + i * 16 + lr;
                af[i]  = *(const bf16x8*)((const char*)Asl + (((ra << 7) + (kk << 6) + hi4) ^ sw));
                bfr[i] = *(const bf16x8*)((const char*)Bs  + (((rb << 7) + (kk << 6) + hi4) ^ sw));
            }
            #pragma unroll
            for (int mi = 0; mi < 4; ++mi)
                #pragma unroll
                for (int ni = 0; ni < 4; ++ni)
                    acc[mi][ni] = __builtin_amdgcn_mfma_f32_16x16x32_bf16(
                        af[mi], bfr[ni], acc[mi][ni], 0, 0, 0);
        }
    }
    const int rbase = m0 + wr + (lane >> 4) * 4;
    const int cbase = wc + lr;                 // n (n0 = 0)
    float s = 0.f, ss = 0.f;
    #pragma unroll
    for (int mi = 0; mi < 4; ++mi)
        #pragma unroll
        for (int ni = 0; ni < 4; ++ni)
            #pragma unroll
            for (int r = 0; r < 4; ++r) {
                long long idx = (long long)(rbase + mi * 16 + r) * Nn + (cbase + ni * 16);
                float zv = acc[mi][ni][r] + X[idx];
                Z1[idx] = (bf16)zv;
                s += zv; ss += zv * zv;
            }
    #pragma unroll
    for (int off = 32; off; off >>= 1) { s += __shfl_xor(s, off); ss += __shfl_xor(ss, off); }
    __shared__ float red[8];
    if (lane == 0) { red[w] = s; red[4 + w] = ss; }
    __syncthreads();
    if (t == 0) {
        float S = red[0] + red[1] + red[2] + red[3];
        float SS = red[4] + red[5] + red[6] + red[7];
        float* p = partials + ((long long)blockIdx.z * 8 + blockIdx.y) * 2;
        p[0] = S; p[1] = SS;
    }
}

// ---------------- hT GEMM: A = XoutT tiled bf16 gload; B = Wf1 f32 reg-staged; relu ----------------
// hT[n,c'] (128 x 1024), grid (8,1,64).
__global__ void __launch_bounds__(256, 2)
gemm_h(const bf16* __restrict__ XoutT, const float* __restrict__ Wf1, bf16* __restrict__ hT) {
    __shared__ char smem[32768];
    bf16* Asl = (bf16*)smem;
    bf16* Bs  = (bf16*)(smem + 16384);
    XoutT += (long long)blockIdx.z * PLANE;
    hT    += (long long)blockIdx.z * ((long long)Nn * Cc);
    const int n0 = blockIdx.x * 128;          // c' offset
    const int t = threadIdx.x, lane = t & 63, w = t >> 6;
    const int wr = (w >> 1) * 64, wc = (w & 1) * 64;
    const int lr = lane & 15, hi4 = (lane >> 4) * 16, sw = (lr & 7) << 4;
    const bf16* gA[4]; int lo[4];
    #pragma unroll
    for (int p = 0; p < 4; ++p) {
        int o = w * 1024 + lane * 16 + p * 4096;
        int row = o >> 7;
        int scol = ((o & 127) ^ ((row & 7) << 4)) >> 1;
        lo[p] = o;
        gA[p] = XoutT + ((long long)(row >> 6) * (Cc >> 6)) * 4096 + (row & 63) * 64 + scol;
    }
    const int s_r = t >> 1, s_k = (t & 1) * 32;   // Wf1 stage: row c' (128)
    float4 wreg[8];
    #pragma unroll
    for (int i = 0; i < 8; ++i)
        wreg[i] = *(const float4*)(Wf1 + (long long)(n0 + s_r) * Cc + s_k + i * 4);
    f32x4 acc[4][4] = {};
    const int NT = Cc / 64;
    for (int kt = 0; kt < NT; ++kt) {
        __syncthreads();   // B1
        #pragma unroll
        for (int p = 0; p < 4; ++p)
            gload_lds16(gA[p] + (long long)kt * 4096, (char*)Asl + lo[p]);
        #pragma unroll
        for (int p = 0; p < 4; ++p) {
            int kc = s_k + p * 8;
            bf16x8 bv;
            #pragma unroll
            for (int j = 0; j < 4; ++j) {
                bv[j]     = (bf16)((const float*)&wreg[p * 2])[j];
                bv[4 + j] = (bf16)((const float*)&wreg[p * 2 + 1])[j];
            }
            *(bf16x8*)((char*)Bs + (((s_r << 7) + kc * 2) ^ ((s_r & 7) << 4))) = bv;
        }
        if (kt + 1 < NT) {
            #pragma unroll
            for (int i = 0; i < 8; ++i)
                wreg[i] = *(const float4*)(Wf1 + (long long)(n0 + s_r) * Cc
                                           + (kt + 1) * 64 + s_k + i * 4);
        }
        __syncthreads();   // B2
        #pragma unroll
        for (int kk = 0; kk < 2; ++kk) {
            bf16x8 af[4], bfr[4];
            #pragma unroll
            for (int i = 0; i < 4; ++i) {
                int ra = wr + i * 16 + lr;
                int rb = wc + i * 16 + lr;
                af[i]  = *(const bf16x8*)((const char*)Asl + (((ra << 7) + (kk << 6) + hi4) ^ sw));
                bfr[i] = *(const bf16x8*)((const char*)Bs  + (((rb << 7) + (kk << 6) + hi4) ^ sw));
            }
            #pragma unroll
            for (int mi = 0; mi < 4; ++mi)
                #pragma unroll
                for (int ni = 0; ni < 4; ++ni)
                    acc[mi][ni] = __builtin_amdgcn_mfma_f32_16x16x32_bf16(
                        af[mi], bfr[ni], acc[mi][ni], 0, 0, 0);
        }
    }
    const int rbase = wr + (lane >> 4) * 4;   // n
    const int cbase = n0 + wc + lr;           // c'
    #pragma unroll
    for (int mi = 0; mi < 4; ++mi)
        #pragma unroll
        for (int ni = 0; ni < 4; ++ni)
            #pragma unroll
            for (int r = 0; r < 4; ++r)
                hT[(long long)(rbase + mi * 16 + r) * Cc + (cbase + ni * 16)] =
                    (bf16)fmaxf(acc[mi][ni][r], 0.0f);
}

// ---------------- FFN GEMM + LN2: A = hT bf16 gload; B = Wf2 f32 reg-staged ----------------
__global__ void __launch_bounds__(256, 2)
gemm_ffn_ln2(const bf16* __restrict__ HT, const float* __restrict__ Wf2,
             const bf16* __restrict__ Z1, const float* __restrict__ pp1,
             const float* __restrict__ gamma, const float* __restrict__ beta,
             bf16* __restrict__ Z2, float* __restrict__ partials) {
    __shared__ char smem[32768];
    bf16* Asl = (bf16*)smem;
    bf16* Bs  = (bf16*)(smem + 16384);
    HT += (long long)blockIdx.z * ((long long)Nn * Cc);
    Z1 += (long long)blockIdx.z * PLANE;
    Z2 += (long long)blockIdx.z * PLANE;
    float S1 = 0.f, SS1 = 0.f;
    #pragma unroll
    for (int j = 0; j < 8; ++j) {
        S1  += pp1[((long long)blockIdx.z * 8 + j) * 2];
        SS1 += pp1[((long long)blockIdx.z * 8 + j) * 2 + 1];
    }
    const float mean1 = S1 * INV_PLANE;
    const float rstd1 = rsqrtf(SS1 * INV_PLANE - mean1 * mean1 + 1e-5f);
    const int n0 = blockIdx.x * 128;          // c' offset
    const int t = threadIdx.x, lane = t & 63, w = t >> 6;
    const int wr = (w >> 1) * 64, wc = (w & 1) * 64;
    const int lr = lane & 15, hi4 = (lane >> 4) * 16, sw = (lr & 7) << 4;
    const bf16* gA[4]; int lo[4];
    #pragma unroll
    for (int p = 0; p < 4; ++p) {
        int o = w * 1024 + lane * 16 + p * 4096;
        int row = o >> 7;
        int scol = ((o & 127) ^ ((row & 7) << 4)) >> 1;
        lo[p] = o;
        gA[p] = HT + (long long)row * Cc + scol;
    }
    const int s_r = t >> 1, s_k = (t & 1) * 32;
    float4 wreg[8];
    #pragma unroll
    for (int i = 0; i < 8; ++i)
        wreg[i] = *(const float4*)(Wf2 + (long long)(n0 + s_r) * Cc + s_k + i * 4);
    f32x4 acc[4][4] = {};
    const int NT = Cc / 64;
    for (int kt = 0; kt < NT; ++kt) {
        __syncthreads();   // B1
        #pragma unroll
        for (int p = 0; p < 4; ++p) gload_lds16(gA[p] + kt * 64, (char*)Asl + lo[p]);
        #pragma unroll
        for (int p = 0; p < 4; ++p) {
            int kc = s_k + p * 8;
            bf16x8 bv;
            #pragma unroll
            for (int j = 0; j < 4; ++j) {
                bv[j]     = (bf16)((const float*)&wreg[p * 2])[j];
                bv[4 + j] = (bf16)((const float*)&wreg[p * 2 + 1])[j];
            }
            *(bf16x8*)((char*)Bs + (((s_r << 7) + kc * 2) ^ ((s_r & 7) << 4))) = bv;
        }
        if (kt + 1 < NT) {
            #pragma unroll
            for (int i = 0; i < 8; ++i)
                wreg[i] = *(const float4*)(Wf2 + (long long)(n0 + s_r) * Cc
                                           + (kt + 1) * 64 + s_k + i * 4);
        }
        __syncthreads();   // B2
        #pragma unroll
        for (int kk = 0; kk < 2; ++kk) {
            bf16x8 af[4], bfr[4];
            #pragma unroll
            for (int i = 0; i < 4; ++i) {
                int ra = wr + i * 16 + lr;
                int rb = wc + i * 16 + lr;
                af[i]  = *(const bf16x8*)((const char*)Asl + (((ra << 7) + (kk << 6) + hi4) ^ sw));
                bfr[i] = *(const bf16x8*)((const char*)Bs  + (((rb << 7) + (kk << 6) + hi4) ^ sw));
            }
            #pragma unroll
            for (int mi = 0; mi < 4; ++mi)
                #pragma unroll
                for (int ni = 0; ni < 4; ++ni)
                    acc[mi][ni] = __builtin_amdgcn_mfma_f32_16x16x32_bf16(
                        af[mi], bfr[ni], acc[mi][ni], 0, 0, 0);
        }
    }
    const int rbase = wr + (lane >> 4) * 4;   // n
    const int cbase = n0 + wc + lr;           // c'
    float s = 0.f, ss = 0.f;
    #pragma unroll
    for (int mi = 0; mi < 4; ++mi)
        #pragma unroll
        for (int ni = 0; ni < 4; ++ni) {
            long long a = (long long)(cbase + ni * 16) * Nn + rbase + mi * 16;
            bf16x4 z1v = *(const bf16x4*)(Z1 + a);
            float4 g  = *(const float4*)(gamma + a);
            float4 be = *(const float4*)(beta + a);
            float x0 = ((float)z1v[0] - mean1) * rstd1 * g.x + be.x;
            float x1 = ((float)z1v[1] - mean1) * rstd1 * g.y + be.y;
            float x2 = ((float)z1v[2] - mean1) * rstd1 * g.z + be.z;
            float x3 = ((float)z1v[3] - mean1) * rstd1 * g.w + be.w;
            float z0 = acc[mi][ni][0] + x0, z1 = acc[mi][ni][1] + x1;
            float z2 = acc[mi][ni][2] + x2, z3 = acc[mi][ni][3] + x3;
            bf16x4 zo = { (bf16)z0, (bf16)z1, (bf16)z2, (bf16)z3 };
            *(bf16x4*)(Z2 + a) = zo;
            s  += z0 + z1 + z2 + z3;
            ss += z0 * z0 + z1 * z1 + z2 * z2 + z3 * z3;
        }
    #pragma unroll
    for (int off = 32; off; off >>= 1) { s += __shfl_xor(s, off); ss += __shfl_xor(ss, off); }
    __shared__ float red[8];
    if (lane == 0) { red[w] = s; red[4 + w] = ss; }
    __syncthreads();
    if (t == 0) {
        float S = red[0] + red[1] + red[2] + red[3];
        float SS = red[4] + red[5] + red[6] + red[7];
        float* p = partials + ((long long)blockIdx.z * 8 + blockIdx.x) * 2;
        p[0] = S; p[1] = SS;
    }
}

// ---------------- LN1 normalize + tiled transposed bf16 output ----------------
__global__ void ln1_norm_transpose(const bf16* __restrict__ Z1, const float* __restrict__ partials,
                                   const float* __restrict__ gamma, const float* __restrict__ beta,
                                   bf16* __restrict__ XoutT) {
    int b = blockIdx.z;
    float S = 0.f, SS = 0.f;
    #pragma unroll
    for (int j = 0; j < 8; ++j) {
        S  += partials[((long long)b * 8 + j) * 2];
        SS += partials[((long long)b * 8 + j) * 2 + 1];
    }
    float mean = S * INV_PLANE;
    float rstd = rsqrtf(SS * INV_PLANE - mean * mean + 1e-5f);
    __shared__ float tile[64][65];
    long long base = (long long)b * PLANE;
    int n0 = blockIdx.x * 64, c0 = blockIdx.y * 64;
    int t = threadIdx.x;
    int rl = t >> 4, sc = (t & 15) * 4;
    #pragma unroll
    for (int p = 0; p < 4; ++p) {
        int r = p * 16 + rl;
        long long idx = (long long)(c0 + r) * Nn + n0 + sc;
        bf16x4 z  = *(const bf16x4*)(Z1 + base + idx);
        float4 g  = *(const float4*)(gamma + idx);
        float4 be = *(const float4*)(beta + idx);
        float4 o = {((float)z[0] - mean) * rstd * g.x + be.x,
                    ((float)z[1] - mean) * rstd * g.y + be.y,
                    ((float)z[2] - mean) * rstd * g.z + be.z,
                    ((float)z[3] - mean) * rstd * g.w + be.w};
        *(float4*)&tile[r][sc] = o;
    }
    __syncthreads();
    long long tb = ((long long)(n0 >> 6) * (Cc >> 6) + (c0 >> 6)) * 4096;
    int sb = t >> 3, rg = (t & 7) * 8;
    #pragma unroll
    for (int p = 0; p < 2; ++p) {
        int n = sb + p * 32;
        bf16x8 o;
        #pragma unroll
        for (int j = 0; j < 8; ++j) o[j] = (bf16)tile[rg + j][n];
        *(bf16x8*)(XoutT + base + tb + n * 64 + rg) = o;
    }
}

// ---------------- final LN ----------------
__global__ void ln2_final(const bf16* __restrict__ Z2, const float* __restrict__ partials,
                          const float* __restrict__ gamma, const float* __restrict__ beta,
                          float* __restrict__ out) {
    int b = blockIdx.y;
    float S = 0.f, SS = 0.f;
    #pragma unroll
    for (int j = 0; j < 8; ++j) {
        S  += partials[((long long)b * 8 + j) * 2];
        SS += partials[((long long)b * 8 + j) * 2 + 1];
    }
    float mean = S * INV_PLANE;
    float rstd = rsqrtf(SS * INV_PLANE - mean * mean + 1e-5f);
    long long base = (long long)b * PLANE;
    int i = (blockIdx.x * 256 + threadIdx.x) * 8;
    bf16x8 z = *(const bf16x8*)(Z2 + base + i);
    #pragma unroll
    for (int h = 0; h < 2; ++h) {
        float4 g  = *(const float4*)(gamma + i + h * 4);
        float4 be = *(const float4*)(beta + i + h * 4);
        float4 o = {((float)z[h * 4 + 0] - mean) * rstd * g.x + be.x,
                    ((float)z[h * 4 + 1] - mean) * rstd * g.y + be.y,
                    ((float)z[h * 4 + 2] - mean) * rstd * g.z + be.z,
                    ((float)z[h * 4 + 3] - mean) * rstd * g.w + be.w};
        *(float4*)(out + base + i + h * 4) = o;
    }
}

extern "C" void kernel_launch(void* const* d_in, const int* in_sizes, int n_in,
                              void* d_out, int out_size, void* d_ws, size_t ws_size,
                              hipStream_t stream) {
    const float* X   = (const float*)d_in[0];
    const float* T   = (const float*)d_in[1];
    const float* Wq  = (const float*)d_in[2];
    const float* Wk  = (const float*)d_in[3];
    const float* Wv  = (const float*)d_in[4];
    const float* Wf1 = (const float*)d_in[5];
    const float* Wf2 = (const float*)d_in[6];
    const float* gamma = (const float*)d_in[7];
    const float* beta  = (const float*)d_in[8];
    float* out = (float*)d_out;
    char* ws = (char*)d_ws;
    const size_t MB = 1ull << 20;

    bf16* WqT  = (bf16*)(ws + 0 * MB);
    bf16* WkT  = (bf16*)(ws + 2 * MB);
    bf16* G2   = (bf16*)(ws + 4 * MB);
    float* G2p = (float*)(ws + 6 * MB);    // 16 MB
    bf16* e    = (bf16*)(ws + 22 * MB);
    bf16* E    = (bf16*)(ws + 38 * MB);    // 8 MB
    bf16* u    = (bf16*)(ws + 46 * MB);
    bf16* Z1   = (bf16*)(ws + 62 * MB);
    bf16* XoutT= (bf16*)(ws + 78 * MB);
    bf16* hT   = (bf16*)(ws + 94 * MB);
    bf16* Z2   = (bf16*)(ws + 110 * MB);
    float* pp1 = (float*)(ws + 126 * MB);
    float* pp2 = (float*)(ws + 126 * MB + 65536);
    float* rsp = (float*)(ws + 127 * MB);  // 256 KB

    dim3 blk256(256);

    // 1. prep: Wq/Wk transposes only
    prep_w<<<dim3(512), blk256, 0, stream>>>(Wq, Wk, WqT, WkT);
    // 2. G2 split-K=4 + reduce
    gemm_tn<float, false, 1, 1><<<dim3(8, 8, 4), blk256, 0, stream>>>(
        WkT, WqT, G2p, Cc, Cc, 256, Cc, 16384, 16384, 1048576, 1.f);
    g2_reduce<<<dim3(1024), blk256, 0, stream>>>(G2p, G2);
    // 3. e = (X f32 transpose-staged)·G2^T
    gemm_e<<<dim3(8, 1, Bb), blk256, 0, stream>>>(X, G2, e);
    // 4. E = exp(sim/32) + rowsum partials
    gemm_sim_exp<<<dim3(8, 1, Bb), blk256, 0, stream>>>(e, T, E, rsp);
    // 5. u = (E·T)/rowsum
    gemm_u_scaled<<<dim3(16, 1, Bb), blk256, 0, stream>>>(E, T, u, rsp);
    // 6. Z1 = (Wv f32-staged)·u^T + X + stats
    gemm_ctx_ln1<<<dim3(1, 8, Bb), blk256, 0, stream>>>(Wv, u, X, Z1, pp1);
    // 7. LN1 -> XoutT tiled
    ln1_norm_transpose<<<dim3(Nn / 64, Cc / 64, Bb), blk256, 0, stream>>>(
        Z1, pp1, gamma, beta, XoutT);
    // 8. hT = relu(XoutT·(Wf1 f32-staged)^T)
    gemm_h<<<dim3(8, 1, Bb), blk256, 0, stream>>>(XoutT, Wf1, hT);
    // 9. Z2 = transpose(hT·(Wf2 f32-staged)^T) + LN1(Z1) + stats
    gemm_ffn_ln2<<<dim3(8, 1, Bb), blk256, 0, stream>>>(
        hT, Wf2, Z1, pp1, gamma, beta, Z2, pp2);
    // 10. LN2 -> out
    ln2_final<<<dim3(64, Bb), blk256, 0, stream>>>(Z2, pp2, gamma, beta, out);
}

// Round 12
// 256.375 us; speedup vs baseline: 1.3294x; 1.3294x over previous
//
#include <hip/hip_runtime.h>

// Transformer decoder block, MI355X gfx950. Round 12: REVERT to round-10
// configuration (best verified: 259.7us). Round 11's fold-staging-into-GEMMs
// was falsified (+81us): exposed gload latency (loads drained at the very
// next barrier, no prefetch distance) at 2 blocks/CU + f32 weight re-reads.
//
// Dataflow:
//   prep: Wv/Wf1/Wf2 casts, WqT/WkT transposes [tiled], Xt [tiled]
//   G2  = WkT·WqT^T (split-K=4, f32 partials -> bf16)
//   e   = Xt · G2^T             (B,N,C)  bf16
//   E   = exp((e·T^T-staged)/32)(B,N,L)  bf16 + row-sum partials
//   u   = (E · T-staged) / rowsum (B,N,C) bf16
//   Z1  = Wv · u^T + X_in       (B,C,N)  bf16 + stats pp1
//   XoutT = LN(Z1) bf16 (N,C) [tiled]
//   hT  = relu(XoutT · Wf1^T)   (B,N,C)  bf16
//   Z2  = transpose(hT·Wf2^T) + LN(Z1)   bf16 + pp2
//   out = LN(Z2) f32

using bf16   = __bf16;
using bf16x4 = __attribute__((ext_vector_type(4))) __bf16;
using bf16x8 = __attribute__((ext_vector_type(8))) __bf16;
using f32x4  = __attribute__((ext_vector_type(4))) float;

static constexpr int  Bb = 64;
static constexpr int  Cc = 1024;
static constexpr int  Nn = 128;
static constexpr int  Ll = 512;
static constexpr long long PLANE = (long long)Cc * Nn;
static constexpr float INV_PLANE = 1.0f / 131072.0f;

__device__ __forceinline__ void gload_lds16(const void* g, void* l) {
    __builtin_amdgcn_global_load_lds(
        (__attribute__((address_space(1))) void*)g,
        (__attribute__((address_space(3))) void*)l,
        16, 0, 0);
}

// ---------------- prep: weight casts + Wq/Wk transposes + Xt (tiled) ----------------
__global__ void __launch_bounds__(256)
prep_all(const float* __restrict__ Wv, const float* __restrict__ Wf1,
         const float* __restrict__ Wf2, const float* __restrict__ Wq,
         const float* __restrict__ Wk, const float* __restrict__ X,
         bf16* __restrict__ WvB, bf16* __restrict__ Wf1B, bf16* __restrict__ Wf2B,
         bf16* __restrict__ WqT, bf16* __restrict__ WkT, bf16* __restrict__ Xt) {
    __shared__ float tile[64][65];
    const int bx = blockIdx.x;
    const int t  = threadIdx.x;
    if (bx < 3072) {
        const float* in = bx < 1024 ? Wv : (bx < 2048 ? Wf1 : Wf2);
        bf16* out       = bx < 1024 ? WvB : (bx < 2048 ? Wf1B : Wf2B);
        int i = (bx & 1023) * 256 + t;
        float4 v = reinterpret_cast<const float4*>(in)[i];
        bf16x4 o = { (bf16)v.x, (bf16)v.y, (bf16)v.z, (bf16)v.w };
        reinterpret_cast<bf16x4*>(out)[i] = o;
        return;
    }
    const float* in; bf16* outT;
    int R, S, bxx, byy, bz = 0;
    if (bx < 3584) {
        int j = bx - 3072;
        in = (j >= 256) ? Wk : Wq; outT = (j >= 256) ? WkT : WqT;
        R = Cc; S = Cc; j &= 255; bxx = j & 15; byy = j >> 4;
    } else {
        int j = bx - 3584; bz = j >> 5; j &= 31;
        bxx = j & 1; byy = j >> 1; in = X; outT = Xt; R = Cc; S = Nn;
    }
    long long plane = (long long)R * S;
    in   += (long long)bz * plane;
    outT += (long long)bz * plane;
    int s0 = bxx * 64, r0 = byy * 64;
    int rl = t >> 4, sc = (t & 15) * 4;
    #pragma unroll
    for (int p = 0; p < 4; ++p) {
        int r = p * 16 + rl;
        float4 v = *(const float4*)(in + (long long)(r0 + r) * S + s0 + sc);
        *(float4*)&tile[r][sc] = v;
    }
    __syncthreads();
    long long tb = ((long long)(s0 >> 6) * (R >> 6) + (r0 >> 6)) * 4096;
    int sb = t >> 3, rg = (t & 7) * 8;
    #pragma unroll
    for (int p = 0; p < 2; ++p) {
        int s = sb + p * 32;
        bf16x8 o;
        #pragma unroll
        for (int j = 0; j < 8; ++j) o[j] = (bf16)tile[rg + j][s];
        *(bf16x8*)(outT + tb + s * 64 + rg) = o;
    }
}

// ---------------- generic TN GEMM core (gload-staged both sides) ----------------
#define GEMM_PROLOGUE_AND_LOOP(A_, Bt_, KLOOP_, LD_, TA_, TB_)                     \
    __shared__ bf16 As[2][128 * 64];                                               \
    __shared__ bf16 Bs[2][128 * 64];                                               \
    const int n0   = blockIdx.x * 128;                                             \
    const int m0   = blockIdx.y * 128;                                             \
    const int t    = threadIdx.x;                                                  \
    const int lane = t & 63;                                                       \
    const int w    = t >> 6;                                                       \
    const int wr   = (w >> 1) * 64;                                                \
    const int wc   = (w & 1) * 64;                                                 \
    const int lr   = lane & 15;                                                    \
    const int hi4  = (lane >> 4) * 16;                                             \
    const int sw   = (lr & 7) << 4;                                                \
    const int stepA_ = (TA_) ? 4096 : 64;                                          \
    const int stepB_ = (TB_) ? 4096 : 64;                                          \
    const bf16* gA[4]; const bf16* gB[4]; int lo[4];                               \
    _Pragma("unroll")                                                              \
    for (int p = 0; p < 4; ++p) {                                                  \
        int o = w * 1024 + lane * 16 + p * 4096;                                   \
        int row = o >> 7;                                                          \
        int scol = ((o & 127) ^ ((row & 7) << 4)) >> 1;                            \
        lo[p] = o;                                                                 \
        int ra = m0 + row, rb = n0 + row;                                          \
        gA[p] = (TA_) ? A_ + ((long long)(ra >> 6) * (LD_ >> 6)) * 4096            \
                           + (ra & 63) * 64 + scol                                 \
                      : A_ + (long long)ra * LD_ + scol;                           \
        gB[p] = (TB_) ? Bt_ + ((long long)(rb >> 6) * (LD_ >> 6)) * 4096           \
                            + (rb & 63) * 64 + scol                                \
                      : Bt_ + (long long)rb * LD_ + scol;                          \
    }                                                                              \
    f32x4 acc[4][4] = {};                                                          \
    const int NT_ = KLOOP_ / 64;                                                   \
    _Pragma("unroll")                                                              \
    for (int p = 0; p < 4; ++p) gload_lds16(gA[p], (char*)As[0] + lo[p]);          \
    _Pragma("unroll")                                                              \
    for (int p = 0; p < 4; ++p) gload_lds16(gB[p], (char*)Bs[0] + lo[p]);          \
    __syncthreads();                                                               \
    int cur_ = 0;                                                                  \
    for (int kt = 0; kt < NT_; ++kt) {                                             \
        if (kt + 1 < NT_) {                                                        \
            _Pragma("unroll")                                                      \
            for (int p = 0; p < 4; ++p)                                            \
                gload_lds16(gA[p] + (long long)(kt + 1) * stepA_,                  \
                            (char*)As[cur_ ^ 1] + lo[p]);                          \
            _Pragma("unroll")                                                      \
            for (int p = 0; p < 4; ++p)                                            \
                gload_lds16(gB[p] + (long long)(kt + 1) * stepB_,                  \
                            (char*)Bs[cur_ ^ 1] + lo[p]);                          \
        }                                                                          \
        const bf16* As_ = As[cur_]; const bf16* Bs_ = Bs[cur_];                    \
        _Pragma("unroll")                                                          \
        for (int kk = 0; kk < 2; ++kk) {                                           \
            bf16x8 af[4], bfr[4];                                                  \
            _Pragma("unroll")                                                      \
            for (int i = 0; i < 4; ++i) {                                          \
                int ra = wr + i * 16 + lr;                                         \
                int rb = wc + i * 16 + lr;                                         \
                af[i]  = *(const bf16x8*)((const char*)As_ +                       \
                          ((((ra << 7) + (kk << 6) + hi4)) ^ sw));                 \
                bfr[i] = *(const bf16x8*)((const char*)Bs_ +                       \
                          ((((rb << 7) + (kk << 6) + hi4)) ^ sw));                 \
            }                                                                      \
            _Pragma("unroll")                                                      \
            for (int mi = 0; mi < 4; ++mi)                                         \
                _Pragma("unroll")                                                  \
                for (int ni = 0; ni < 4; ++ni)                                     \
                    acc[mi][ni] = __builtin_amdgcn_mfma_f32_16x16x32_bf16(         \
                        af[mi], bfr[ni], acc[mi][ni], 0, 0, 0);                    \
        }                                                                          \
        __syncthreads();                                                           \
        cur_ ^= 1;                                                                 \
    }

template <typename OutT, bool RELU, int TA, int TB>
__global__ void __launch_bounds__(256, 2)
gemm_tn(const bf16* __restrict__ A, const bf16* __restrict__ Bt, OutT* __restrict__ C,
        int M, int N, int KLOOP, int ld, long long sA, long long sBt, long long sC,
        float scale) {
    A  += (long long)blockIdx.z * sA;
    Bt += (long long)blockIdx.z * sBt;
    C  += (long long)blockIdx.z * sC;
    GEMM_PROLOGUE_AND_LOOP(A, Bt, KLOOP, ld, TA, TB)
    const int rbase = m0 + wr + (lane >> 4) * 4;
    const int cbase = n0 + wc + lr;
    #pragma unroll
    for (int mi = 0; mi < 4; ++mi)
        #pragma unroll
        for (int ni = 0; ni < 4; ++ni)
            #pragma unroll
            for (int r = 0; r < 4; ++r) {
                float v = acc[mi][ni][r] * scale;
                if (RELU) v = fmaxf(v, 0.0f);
                C[(long long)(rbase + mi * 16 + r) * N + (cbase + ni * 16)] = (OutT)v;
            }
}

__global__ void g2_reduce(const float* __restrict__ p, bf16* __restrict__ g2) {
    int i = (blockIdx.x * 256 + threadIdx.x) * 4;
    float4 a = *(const float4*)(p + i);
    float4 b = *(const float4*)(p + 1048576 + i);
    float4 c = *(const float4*)(p + 2097152 + i);
    float4 d = *(const float4*)(p + 3145728 + i);
    bf16x4 o = { (bf16)(a.x + b.x + c.x + d.x), (bf16)(a.y + b.y + c.y + d.y),
                 (bf16)(a.z + b.z + c.z + d.z), (bf16)(a.w + b.w + c.w + d.w) };
    *(bf16x4*)(g2 + i) = o;
}

// ---------------- sim GEMM: 128(n) x 64(l) tile, grid (8,1,B) = 512 blocks ----------------
__global__ void __launch_bounds__(256, 2)
gemm_sim_exp(const bf16* __restrict__ A /*e*/, const float* __restrict__ Tg,
             bf16* __restrict__ E, float* __restrict__ rspart) {
    __shared__ char smem[33024];               // As 16384 + Bs 8192 + scr 8448
    bf16* Asb = (bf16*)smem;
    bf16* Bs  = (bf16*)(smem + 16384);
    bf16* scr = (bf16*)(smem + 24576);         // [64][66] bf16
    A  += (long long)blockIdx.z * ((long long)Nn * Cc);
    Tg += (long long)blockIdx.z * ((long long)Cc * Ll);
    E  += (long long)blockIdx.z * ((long long)Nn * Ll);
    const int l0 = blockIdx.x * 64;
    const int t = threadIdx.x, lane = t & 63, w = t >> 6;
    const int lr = lane & 15, hi4 = (lane >> 4) * 16, sw = (lr & 7) << 4;
    const bf16* gA[4]; int lo[4];
    #pragma unroll
    for (int p = 0; p < 4; ++p) {
        int o = w * 1024 + lane * 16 + p * 4096;
        int row = o >> 7;
        int scol = ((o & 127) ^ ((row & 7) << 4)) >> 1;
        lo[p] = o;
        gA[p] = A + (long long)row * Cc + scol;
    }
    const int s_c = t >> 2, s_l = (t & 3) * 16;
    float4 treg[4];
    #pragma unroll
    for (int i = 0; i < 4; ++i)
        treg[i] = *(const float4*)(Tg + (long long)s_c * Ll + l0 + s_l + i * 4);
    f32x4 acc[2][4] = {};
    const int NT = Cc / 64;
    for (int kt = 0; kt < NT; ++kt) {
        #pragma unroll
        for (int i = 0; i < 4; ++i) {
            float4 v = treg[i];
            bf16x4 o = { (bf16)v.x, (bf16)v.y, (bf16)v.z, (bf16)v.w };
            *(bf16x4*)(scr + s_c * 66 + s_l + i * 4) = o;
        }
        __syncthreads();   // B1: scr visible; prior MFMA reads of As/Bs done
        #pragma unroll
        for (int p = 0; p < 4; ++p) gload_lds16(gA[p] + kt * 64, (char*)Asb + lo[p]);
        {
            int lrow = t & 63;
            #pragma unroll
            for (int p = 0; p < 2; ++p) {
                int c8 = (t >> 6) * 16 + p * 8;
                bf16x8 bv;
                #pragma unroll
                for (int j = 0; j < 8; ++j) bv[j] = scr[(c8 + j) * 66 + lrow];
                *(bf16x8*)((char*)Bs + (((lrow << 7) + c8 * 2) ^ ((lrow & 7) << 4))) = bv;
            }
        }
        if (kt + 1 < NT) {
            #pragma unroll
            for (int i = 0; i < 4; ++i)
                treg[i] = *(const float4*)(Tg + (long long)((kt + 1) * 64 + s_c) * Ll
                                           + l0 + s_l + i * 4);
        }
        __syncthreads();   // B2: Bs visible + As gloads drained
        #pragma unroll
        for (int kk = 0; kk < 2; ++kk) {
            bf16x8 af[2], bfr[4];
            #pragma unroll
            for (int mi = 0; mi < 2; ++mi) {
                int ra = w * 32 + mi * 16 + lr;
                af[mi] = *(const bf16x8*)((const char*)Asb + (((ra << 7) + (kk << 6) + hi4) ^ sw));
            }
            #pragma unroll
            for (int ni = 0; ni < 4; ++ni) {
                int rb = ni * 16 + lr;
                bfr[ni] = *(const bf16x8*)((const char*)Bs + (((rb << 7) + (kk << 6) + hi4) ^ sw));
            }
            #pragma unroll
            for (int mi = 0; mi < 2; ++mi)
                #pragma unroll
                for (int ni = 0; ni < 4; ++ni)
                    acc[mi][ni] = __builtin_amdgcn_mfma_f32_16x16x32_bf16(
                        af[mi], bfr[ni], acc[mi][ni], 0, 0, 0);
        }
    }
    float psum[2][4];
    #pragma unroll
    for (int mi = 0; mi < 2; ++mi)
        #pragma unroll
        for (int r = 0; r < 4; ++r) psum[mi][r] = 0.f;
    #pragma unroll
    for (int mi = 0; mi < 2; ++mi)
        #pragma unroll
        for (int ni = 0; ni < 4; ++ni)
            #pragma unroll
            for (int r = 0; r < 4; ++r) {
                int row = w * 32 + mi * 16 + (lane >> 4) * 4 + r;
                float ev = __expf(acc[mi][ni][r] * 0.03125f);
                E[(long long)row * Ll + l0 + ni * 16 + lr] = (bf16)ev;
                psum[mi][r] += ev;
            }
    #pragma unroll
    for (int mi = 0; mi < 2; ++mi)
        #pragma unroll
        for (int r = 0; r < 4; ++r) {
            float v = psum[mi][r];
            v += __shfl_xor(v, 1); v += __shfl_xor(v, 2);
            v += __shfl_xor(v, 4); v += __shfl_xor(v, 8);
            psum[mi][r] = v;
        }
    if (lr == 0) {
        float* rp = rspart + ((long long)blockIdx.z * 8 + blockIdx.x) * 128;
        #pragma unroll
        for (int mi = 0; mi < 2; ++mi)
            #pragma unroll
            for (int r = 0; r < 4; ++r)
                rp[w * 32 + mi * 16 + (lane >> 4) * 4 + r] = psum[mi][r];
    }
}

// ---------------- u GEMM: 128(n) x 64(c) tile, grid (16,1,B) = 1024 blocks ----------------
__global__ void __launch_bounds__(256, 4)
gemm_u_scaled(const bf16* __restrict__ A /*E*/, const float* __restrict__ Tg,
              bf16* __restrict__ C, const float* __restrict__ rspart) {
    __shared__ char smem[40960];               // As dbuf 32768 + Bs 8192
    bf16* AsB = (bf16*)smem;
    bf16* Bs  = (bf16*)(smem + 32768);
    A  += (long long)blockIdx.z * ((long long)Nn * Ll);
    Tg += (long long)blockIdx.z * ((long long)Cc * Ll);
    C  += (long long)blockIdx.z * ((long long)Nn * Cc);
    const float* rp = rspart + (long long)blockIdx.z * 1024;
    const int c0 = blockIdx.x * 64;
    const int t = threadIdx.x, lane = t & 63, w = t >> 6;
    const int lr = lane & 15, hi4 = (lane >> 4) * 16, sw = (lr & 7) << 4;
    const bf16* gA[4]; int lo[4];
    #pragma unroll
    for (int p = 0; p < 4; ++p) {
        int o = w * 1024 + lane * 16 + p * 4096;
        int row = o >> 7;
        int scol = ((o & 127) ^ ((row & 7) << 4)) >> 1;
        lo[p] = o;
        gA[p] = A + (long long)row * Ll + scol;
    }
    const int s_c = t >> 2, s_l = (t & 3) * 16;
    float4 treg[4];
    #pragma unroll
    for (int p = 0; p < 4; ++p) gload_lds16(gA[p], (char*)AsB + lo[p]);
    #pragma unroll
    for (int i = 0; i < 4; ++i)
        treg[i] = *(const float4*)(Tg + (long long)(c0 + s_c) * Ll + s_l + i * 4);
    f32x4 acc[2][4] = {};
    int cur = 0;
    const int NT = Ll / 64;
    for (int kt = 0; kt < NT; ++kt) {
        if (kt + 1 < NT) {
            #pragma unroll
            for (int p = 0; p < 4; ++p)
                gload_lds16(gA[p] + (kt + 1) * 64, (char*)AsB + (cur ^ 1) * 16384 + lo[p]);
        }
        __syncthreads();
        #pragma unroll
        for (int p = 0; p < 2; ++p) {
            bf16x8 bv;
            #pragma unroll
            for (int j = 0; j < 4; ++j) {
                bv[j]     = (bf16)((const float*)&treg[p * 2])[j];
                bv[4 + j] = (bf16)((const float*)&treg[p * 2 + 1])[j];
            }
            *(bf16x8*)((char*)Bs + (((s_c << 7) + (s_l + p * 8) * 2) ^ ((s_c & 7) << 4))) = bv;
        }
        if (kt + 1 < NT) {
            #pragma unroll
            for (int i = 0; i < 4; ++i)
                treg[i] = *(const float4*)(Tg + (long long)(c0 + s_c) * Ll
                                           + (kt + 1) * 64 + s_l + i * 4);
        }
        __syncthreads();
        const bf16* As_ = AsB + cur * 8192;
        #pragma unroll
        for (int kk = 0; kk < 2; ++kk) {
            bf16x8 af[2], bfr[4];
            #pragma unroll
            for (int mi = 0; mi < 2; ++mi) {
                int ra = w * 32 + mi * 16 + lr;
                af[mi] = *(const bf16x8*)((const char*)As_ + (((ra << 7) + (kk << 6) + hi4) ^ sw));
            }
            #pragma unroll
            for (int ni = 0; ni < 4; ++ni) {
                int rb = ni * 16 + lr;
                bfr[ni] = *(const bf16x8*)((const char*)Bs + (((rb << 7) + (kk << 6) + hi4) ^ sw));
            }
            #pragma unroll
            for (int mi = 0; mi < 2; ++mi)
                #pragma unroll
                for (int ni = 0; ni < 4; ++ni)
                    acc[mi][ni] = __builtin_amdgcn_mfma_f32_16x16x32_bf16(
                        af[mi], bfr[ni], acc[mi][ni], 0, 0, 0);
        }
        cur ^= 1;
    }
    #pragma unroll
    for (int mi = 0; mi < 2; ++mi)
        #pragma unroll
        for (int r = 0; r < 4; ++r) {
            int row = w * 32 + mi * 16 + (lane >> 4) * 4 + r;
            float s = 0.f;
            #pragma unroll
            for (int j = 0; j < 8; ++j) s += rp[j * 128 + row];
            float inv = 1.f / s;
            #pragma unroll
            for (int ni = 0; ni < 4; ++ni)
                C[(long long)row * Cc + (c0 + ni * 16 + lr)] = (bf16)(acc[mi][ni][r] * inv);
        }
}

// ctx GEMM + LN1 residual/stats epilogue (Z1 bf16):
__global__ void __launch_bounds__(256, 2)
gemm_ctx_ln1(const bf16* __restrict__ A /*Wv*/, const bf16* __restrict__ Bt /*u*/,
             const float* __restrict__ X, bf16* __restrict__ Z1, float* __restrict__ partials,
             int K, long long sBt) {
    const int N = Nn;
    Bt += (long long)blockIdx.z * sBt;
    X  += (long long)blockIdx.z * PLANE;
    Z1 += (long long)blockIdx.z * PLANE;
    GEMM_PROLOGUE_AND_LOOP(A, Bt, K, K, 0, 0)
    const int rbase = m0 + wr + (lane >> 4) * 4;
    const int cbase = n0 + wc + lr;
    float s = 0.f, ss = 0.f;
    #pragma unroll
    for (int mi = 0; mi < 4; ++mi)
        #pragma unroll
        for (int ni = 0; ni < 4; ++ni)
            #pragma unroll
            for (int r = 0; r < 4; ++r) {
                long long idx = (long long)(rbase + mi * 16 + r) * N + (cbase + ni * 16);
                float zv = acc[mi][ni][r] + X[idx];
                Z1[idx] = (bf16)zv;
                s += zv; ss += zv * zv;
            }
    #pragma unroll
    for (int off = 32; off; off >>= 1) { s += __shfl_xor(s, off); ss += __shfl_xor(ss, off); }
    __shared__ float red[8];
    if (lane == 0) { red[w] = s; red[4 + w] = ss; }
    __syncthreads();
    if (t == 0) {
        float S = red[0] + red[1] + red[2] + red[3];
        float SS = red[4] + red[5] + red[6] + red[7];
        float* p = partials + ((long long)blockIdx.z * 8 + blockIdx.y) * 2;
        p[0] = S; p[1] = SS;
    }
}

// FFN GEMM + LN2 epilogue (Xout recomputed from bf16 Z1 + pp1; Z2 bf16):
__global__ void __launch_bounds__(256, 2)
gemm_ffn_ln2(const bf16* __restrict__ A /*hT*/, const bf16* __restrict__ Bt /*Wf2*/,
             const bf16* __restrict__ Z1, const float* __restrict__ pp1,
             const float* __restrict__ gamma, const float* __restrict__ beta,
             bf16* __restrict__ Z2, float* __restrict__ partials,
             int K, long long sA) {
    A  += (long long)blockIdx.z * sA;
    Z1 += (long long)blockIdx.z * PLANE;
    Z2 += (long long)blockIdx.z * PLANE;
    float S1 = 0.f, SS1 = 0.f;
    #pragma unroll
    for (int j = 0; j < 8; ++j) {
        S1  += pp1[((long long)blockIdx.z * 8 + j) * 2];
        SS1 += pp1[((long long)blockIdx.z * 8 + j) * 2 + 1];
    }
    const float mean1 = S1 * INV_PLANE;
    const float rstd1 = rsqrtf(SS1 * INV_PLANE - mean1 * mean1 + 1e-5f);
    GEMM_PROLOGUE_AND_LOOP(A, Bt, K, K, 0, 0)
    const int rbase = m0 + wr + (lane >> 4) * 4;
    const int cbase = n0 + wc + lr;
    float s = 0.f, ss = 0.f;
    #pragma unroll
    for (int mi = 0; mi < 4; ++mi)
        #pragma unroll
        for (int ni = 0; ni < 4; ++ni) {
            long long a = (long long)(cbase + ni * 16) * Nn + rbase + mi * 16;
            bf16x4 z1v = *(const bf16x4*)(Z1 + a);
            float4 g  = *(const float4*)(gamma + a);
            float4 be = *(const float4*)(beta + a);
            float x0 = ((float)z1v[0] - mean1) * rstd1 * g.x + be.x;
            float x1 = ((float)z1v[1] - mean1) * rstd1 * g.y + be.y;
            float x2 = ((float)z1v[2] - mean1) * rstd1 * g.z + be.z;
            float x3 = ((float)z1v[3] - mean1) * rstd1 * g.w + be.w;
            float z0 = acc[mi][ni][0] + x0, z1 = acc[mi][ni][1] + x1;
            float z2 = acc[mi][ni][2] + x2, z3 = acc[mi][ni][3] + x3;
            bf16x4 zo = { (bf16)z0, (bf16)z1, (bf16)z2, (bf16)z3 };
            *(bf16x4*)(Z2 + a) = zo;
            s  += z0 + z1 + z2 + z3;
            ss += z0 * z0 + z1 * z1 + z2 * z2 + z3 * z3;
        }
    #pragma unroll
    for (int off = 32; off; off >>= 1) { s += __shfl_xor(s, off); ss += __shfl_xor(ss, off); }
    __shared__ float red[8];
    if (lane == 0) { red[w] = s; red[4 + w] = ss; }
    __syncthreads();
    if (t == 0) {
        float S = red[0] + red[1] + red[2] + red[3];
        float SS = red[4] + red[5] + red[6] + red[7];
        float* p = partials + ((long long)blockIdx.z * 8 + blockIdx.x) * 2;
        p[0] = S; p[1] = SS;
    }
}

// ---------------- LN1 normalize + tiled transposed bf16 output ----------------
__global__ void ln1_norm_transpose(const bf16* __restrict__ Z1, const float* __restrict__ partials,
                                   const float* __restrict__ gamma, const float* __restrict__ beta,
                                   bf16* __restrict__ XoutT) {
    int b = blockIdx.z;
    float S = 0.f, SS = 0.f;
    #pragma unroll
    for (int j = 0; j < 8; ++j) {
        S  += partials[((long long)b * 8 + j) * 2];
        SS += partials[((long long)b * 8 + j) * 2 + 1];
    }
    float mean = S * INV_PLANE;
    float rstd = rsqrtf(SS * INV_PLANE - mean * mean + 1e-5f);
    __shared__ float tile[64][65];
    long long base = (long long)b * PLANE;
    int n0 = blockIdx.x * 64, c0 = blockIdx.y * 64;
    int t = threadIdx.x;
    int rl = t >> 4, sc = (t & 15) * 4;
    #pragma unroll
    for (int p = 0; p < 4; ++p) {
        int r = p * 16 + rl;
        long long idx = (long long)(c0 + r) * Nn + n0 + sc;
        bf16x4 z  = *(const bf16x4*)(Z1 + base + idx);
        float4 g  = *(const float4*)(gamma + idx);
        float4 be = *(const float4*)(beta + idx);
        float4 o = {((float)z[0] - mean) * rstd * g.x + be.x,
                    ((float)z[1] - mean) * rstd * g.y + be.y,
                    ((float)z[2] - mean) * rstd * g.z + be.z,
                    ((float)z[3] - mean) * rstd * g.w + be.w};
        *(float4*)&tile[r][sc] = o;
    }
    __syncthreads();
    long long tb = ((long long)(n0 >> 6) * (Cc >> 6) + (c0 >> 6)) * 4096;
    int sb = t >> 3, rg = (t & 7) * 8;
    #pragma unroll
    for (int p = 0; p < 2; ++p) {
        int n = sb + p * 32;
        bf16x8 o;
        #pragma unroll
        for (int j = 0; j < 8; ++j) o[j] = (bf16)tile[rg + j][n];
        *(bf16x8*)(XoutT + base + tb + n * 64 + rg) = o;
    }
}

// ---------------- final LN ----------------
__global__ void ln2_final(const bf16* __restrict__ Z2, const float* __restrict__ partials,
                          const float* __restrict__ gamma, const float* __restrict__ beta,
                          float* __restrict__ out) {
    int b = blockIdx.y;
    float S = 0.f, SS = 0.f;
    #pragma unroll
    for (int j = 0; j < 8; ++j) {
        S  += partials[((long long)b * 8 + j) * 2];
        SS += partials[((long long)b * 8 + j) * 2 + 1];
    }
    float mean = S * INV_PLANE;
    float rstd = rsqrtf(SS * INV_PLANE - mean * mean + 1e-5f);
    long long base = (long long)b * PLANE;
    int i = (blockIdx.x * 256 + threadIdx.x) * 8;
    bf16x8 z = *(const bf16x8*)(Z2 + base + i);
    #pragma unroll
    for (int h = 0; h < 2; ++h) {
        float4 g  = *(const float4*)(gamma + i + h * 4);
        float4 be = *(const float4*)(beta + i + h * 4);
        float4 o = {((float)z[h * 4 + 0] - mean) * rstd * g.x + be.x,
                    ((float)z[h * 4 + 1] - mean) * rstd * g.y + be.y,
                    ((float)z[h * 4 + 2] - mean) * rstd * g.z + be.z,
                    ((float)z[h * 4 + 3] - mean) * rstd * g.w + be.w};
        *(float4*)(out + base + i + h * 4) = o;
    }
}

extern "C" void kernel_launch(void* const* d_in, const int* in_sizes, int n_in,
                              void* d_out, int out_size, void* d_ws, size_t ws_size,
                              hipStream_t stream) {
    const float* X   = (const float*)d_in[0];
    const float* T   = (const float*)d_in[1];
    const float* Wq  = (const float*)d_in[2];
    const float* Wk  = (const float*)d_in[3];
    const float* Wv  = (const float*)d_in[4];
    const float* Wf1 = (const float*)d_in[5];
    const float* Wf2 = (const float*)d_in[6];
    const float* gamma = (const float*)d_in[7];
    const float* beta  = (const float*)d_in[8];
    float* out = (float*)d_out;
    char* ws = (char*)d_ws;
    const size_t MB = 1ull << 20;

    bf16* WvB  = (bf16*)(ws + 0 * MB);
    bf16* Wf1B = (bf16*)(ws + 2 * MB);
    bf16* Wf2B = (bf16*)(ws + 4 * MB);
    bf16* WqT  = (bf16*)(ws + 6 * MB);
    bf16* WkT  = (bf16*)(ws + 8 * MB);
    bf16* G2   = (bf16*)(ws + 10 * MB);
    bf16* Xt   = (bf16*)(ws + 12 * MB);
    bf16* Z1   = (bf16*)(ws + 28 * MB);
    bf16* XoutT= (bf16*)(ws + 44 * MB);
    bf16* hT   = (bf16*)(ws + 60 * MB);
    bf16* e    = (bf16*)(ws + 76 * MB);
    bf16* Z2   = (bf16*)(ws + 92 * MB);
    bf16* E    = (bf16*)(ws + 108 * MB);
    bf16* u    = (bf16*)(ws + 116 * MB);
    float* G2p = (float*)(ws + 132 * MB);
    float* pp1 = (float*)(ws + 148 * MB);
    float* pp2 = (float*)(ws + 148 * MB + 65536);
    float* rsp = (float*)(ws + 149 * MB);    // 256 KB

    dim3 blk256(256);

    prep_all<<<dim3(5632), blk256, 0, stream>>>(
        Wv, Wf1, Wf2, Wq, Wk, X, WvB, Wf1B, Wf2B, WqT, WkT, Xt);

    gemm_tn<float, false, 1, 1><<<dim3(8, 8, 4), blk256, 0, stream>>>(
        WkT, WqT, G2p, Cc, Cc, 256, Cc, 16384, 16384, 1048576, 1.f);
    g2_reduce<<<dim3(1024), blk256, 0, stream>>>(G2p, G2);

    gemm_tn<bf16, false, 1, 0><<<dim3(8, 1, Bb), blk256, 0, stream>>>(
        Xt, G2, e, Nn, Cc, Cc, Cc, (long long)Nn * Cc, 0, (long long)Nn * Cc, 1.f);
    gemm_sim_exp<<<dim3(8, 1, Bb), blk256, 0, stream>>>(e, T, E, rsp);
    gemm_u_scaled<<<dim3(16, 1, Bb), blk256, 0, stream>>>(E, T, u, rsp);
    gemm_ctx_ln1<<<dim3(1, 8, Bb), blk256, 0, stream>>>(
        WvB, u, X, Z1, pp1, Cc, (long long)Nn * Cc);
    ln1_norm_transpose<<<dim3(Nn / 64, Cc / 64, Bb), blk256, 0, stream>>>(
        Z1, pp1, gamma, beta, XoutT);
    gemm_tn<bf16, true, 1, 0><<<dim3(8, 1, Bb), blk256, 0, stream>>>(
        XoutT, Wf1B, hT, Nn, Cc, Cc, Cc, (long long)Nn * Cc, 0, (long long)Nn * Cc, 1.f);
    gemm_ffn_ln2<<<dim3(8, 1, Bb), blk256, 0, stream>>>(
        hT, Wf2B, Z1, pp1, gamma, beta, Z2, pp2, Cc, (long long)Nn * Cc);
    ln2_final<<<dim3(64, Bb), blk256, 0, stream>>>(Z2, pp2, gamma, beta, out);
}